// Round 9
// baseline (170.973 us; speedup 1.0000x reference)
//
#include <hip/hip_runtime.h>
#include <stdint.h>

#define CC 256
#define NN 4096   // H*W = 64*64

typedef __attribute__((ext_vector_type(8))) short short8;
typedef __attribute__((ext_vector_type(4))) float floatx4;
typedef __attribute__((ext_vector_type(4))) unsigned int uint4v;
typedef __attribute__((ext_vector_type(2))) unsigned int uint2v;

__device__ __forceinline__ unsigned short f2bf(float f) {
    unsigned int u = __builtin_bit_cast(unsigned int, f);
    u = (u + 0x7FFFu + ((u >> 16) & 1u)) >> 16;   // RNE
    return (unsigned short)u;
}

__device__ __forceinline__ floatx4 mfma16(short8 a, short8 b, floatx4 c) {
    return __builtin_amdgcn_mfma_f32_16x16x32_bf16(a, b, c, 0, 0, 0);
}

// ---------------------------------------------------------------------------
// Fragment layouts (16x16x32 bf16; A-frag == B-frag lane map:
//   element(row = 16*tile + (lane&15), k = 32*kk + (lane>>4)*8 + j)):
// xB[b][nt 256][kk 8][lane][j] : row = n (pixel), k = c   (S A- and B-operands)
// xG[b][mt 64][cct 16][kk2 2][lane][j] : row = c, k = m   (G2 A-operand)
// wF[ct 16][kk 8][lane][j]     : row = out-c, k = in-c    (epilogue A)
// All R6/R7/R8-proven.
// ---------------------------------------------------------------------------

// ---------------------------------------------------------------------------
// k_trans: x -> xB + xG (bf16 fragment-ordered) + partial norms psum.
// (R7 verbatim)
// ---------------------------------------------------------------------------
__global__ __launch_bounds__(256) void k_trans(const float* __restrict__ x,
                                               unsigned short* __restrict__ xB,
                                               unsigned short* __restrict__ xG,
                                               float* __restrict__ psum) {
    int blk = blockIdx.x;
    int b  = blk >> 8;
    int cc = (blk >> 6) & 3;
    int nc = blk & 63;
    int c0 = cc << 6, n0 = nc << 6;
    __shared__ float tile[64][65];     // [c-local][n-local], +1 pad
    __shared__ float red[4][64];
    int t = threadIdx.x;
    {
        int c   = t >> 2;
        int nn4 = (t & 3) << 4;
        const float* src = x + (size_t)(b * CC + c0 + c) * NN + n0 + nn4;
        #pragma unroll
        for (int j = 0; j < 16; j += 4) {
            floatx4 v = *(const floatx4*)(src + j);
            tile[c][nn4 + j + 0] = v[0];
            tile[c][nn4 + j + 1] = v[1];
            tile[c][nn4 + j + 2] = v[2];
            tile[c][nn4 + j + 3] = v[3];
        }
    }
    __syncthreads();
    int g = t >> 6, lane = t & 63, l15 = lane & 15, q = lane >> 4;
    #pragma unroll
    for (int kkl = 0; kkl < 2; ++kkl) {
        unsigned int w[4];
        #pragma unroll
        for (int j = 0; j < 4; ++j) {
            unsigned int lo = f2bf(tile[32 * kkl + 8 * q + 2 * j][16 * g + l15]);
            unsigned int hi = f2bf(tile[32 * kkl + 8 * q + 2 * j + 1][16 * g + l15]);
            w[j] = lo | (hi << 16);
        }
        uint4v p = {w[0], w[1], w[2], w[3]};
        *(uint4v*)(xB + ((size_t)(b * 256 + (n0 >> 4) + g) * 8 + (c0 >> 5) + kkl) * 512
                   + lane * 8) = p;
    }
    #pragma unroll
    for (int kk2 = 0; kk2 < 2; ++kk2) {
        unsigned int w[4];
        #pragma unroll
        for (int j = 0; j < 4; ++j) {
            unsigned int lo = f2bf(tile[16 * g + l15][32 * kk2 + 8 * q + 2 * j]);
            unsigned int hi = f2bf(tile[16 * g + l15][32 * kk2 + 8 * q + 2 * j + 1]);
            w[j] = lo | (hi << 16);
        }
        uint4v p = {w[0], w[1], w[2], w[3]};
        *(uint4v*)(xG + (size_t)(b * 64 + nc) * 16 * 1024
                   + ((size_t)((c0 >> 4) + g)) * 1024 + kk2 * 512 + lane * 8) = p;
    }
    {
        int n  = t & 63;
        int cq = t >> 6;
        float ss = 0.f;
        #pragma unroll
        for (int i = 0; i < 16; ++i) {
            float v = tile[cq * 16 + i][n];
            ss = fmaf(v, v, ss);
        }
        red[cq][n] = ss;
    }
    __syncthreads();
    if (t < 64) {
        float s = red[0][t] + red[1][t] + red[2][t] + red[3][t];
        psum[((size_t)(b * 64 + nc) * 64 + t) * 4 + cc] = s;
    }
}

// ---------------------------------------------------------------------------
// k_invwcast (R7 verbatim)
// ---------------------------------------------------------------------------
__global__ __launch_bounds__(256) void k_invwcast(const float* __restrict__ psum,
                                                  float* __restrict__ invn,
                                                  const float* __restrict__ Wm,
                                                  unsigned short* __restrict__ wF) {
    int bid = blockIdx.x;
    int t = threadIdx.x;
    if (bid < 64) {
        int i = bid * 256 + t;
        floatx4 p = *(const floatx4*)(psum + (size_t)i * 4);
        float ss = (p[0] + p[1]) + (p[2] + p[3]);
        invn[i] = 1.f / fmaxf(sqrtf(ss), 1e-8f);
    } else {
        int idx = (bid - 64) * 256 + t;          // 0..8191
        int f = idx >> 6, lane = idx & 63;
        int ct = f >> 3, kk = f & 7;
        int l15 = lane & 15, q = lane >> 4;
        const float* src = Wm + (size_t)(16 * ct + l15) * CC + 32 * kk + 8 * q;
        floatx4 a = *(const floatx4*)src;
        floatx4 c = *(const floatx4*)(src + 4);
        unsigned int w0 = f2bf(a[0]) | ((unsigned int)f2bf(a[1]) << 16);
        unsigned int w1 = f2bf(a[2]) | ((unsigned int)f2bf(a[3]) << 16);
        unsigned int w2 = f2bf(c[0]) | ((unsigned int)f2bf(c[1]) << 16);
        unsigned int w3 = f2bf(c[2]) | ((unsigned int)f2bf(c[3]) << 16);
        uint4v p = {w0, w1, w2, w3};
        *(uint4v*)(wF + (size_t)f * 512 + lane * 8) = p;
    }
}

// ---------------------------------------------------------------------------
// k_fused v8: Q-tile 32, 256 thr (4 waves), grid 512 -> 2 blocks/CU.
// Two independent barrier groups per CU decouple the S/P/G2 phases.
// Wave wv: S ms=wv (both nq-subtiles); G2+epilogue ct in {wv,wv+4,wv+8,wv+12}.
// bq one-step-ahead register double-buffer (R8-proven); single lgkm-only
// barrier per step; reassociated epilogue (R6-proven).
// ---------------------------------------------------------------------------
#define FUSED_STEP(IT, BQC, BQN, PB)                                           \
    {                                                                          \
        int m0 = (IT) << 6;                                                    \
        int itn = ((IT) < 63) ? (IT) + 1 : 63;                                 \
        /* issue NEXT step's key B-frags (consumed next step) */               \
        _Pragma("unroll")                                                      \
        for (int kk = 0; kk < 8; ++kk)                                         \
            BQN[kk] = *(const short8*)(xBb                                     \
                + ((size_t)(itn * 4 + ms) * 8 + kk) * 512 + lane * 8);         \
        /* xg A-frags for THIS step (consumed after barrier) */                \
        short8 xg[4][2];                                                       \
        _Pragma("unroll")                                                      \
        for (int ci = 0; ci < 4; ++ci)                                         \
            _Pragma("unroll")                                                  \
            for (int kk2 = 0; kk2 < 2; ++kk2)                                  \
                xg[ci][kk2] = *(const short8*)(xGb                             \
                    + (size_t)((IT) * 16 + wv + 4 * ci) * 1024                 \
                    + kk2 * 512 + lane * 8);                                   \
        float invm = invb[m0 + 16 * ms + l15];                                 \
        /* S = Xq^T Xm using CURRENT (prefetched) bq */                        \
        floatx4 s0a = zero4, s0b = zero4, s1a = zero4, s1b = zero4;            \
        _Pragma("unroll")                                                      \
        for (int kk = 0; kk < 8; kk += 2) {                                    \
            s0a = mfma16(aq[0][kk],     BQC[kk],     s0a);                     \
            s1a = mfma16(aq[1][kk],     BQC[kk],     s1a);                     \
            s0b = mfma16(aq[0][kk + 1], BQC[kk + 1], s0b);                     \
            s1b = mfma16(aq[1][kk + 1], BQC[kk + 1], s1b);                     \
        }                                                                      \
        /* P = relu(S*inv)^2 -> PB (scalar writes) + csum */                   \
        _Pragma("unroll")                                                      \
        for (int s = 0; s < 2; ++s) {                                          \
            floatx4 sv = (s == 0) ? (s0a + s0b) : (s1a + s1b);                 \
            unsigned short* pw = PB + (16 * s) * 72 + 16 * ms + l15;           \
            _Pragma("unroll")                                                  \
            for (int i = 0; i < 4; ++i) {                                      \
                float v = sv[i] * (invq[s][i] * invm);                         \
                v = fmaxf(v, 0.f);                                             \
                v = v * v;                                                     \
                csum[s][i] += v;                                               \
                pw[(q * 4 + i) * 72] = f2bf(v);                                \
            }                                                                  \
        }                                                                      \
        asm volatile("s_waitcnt lgkmcnt(0)\n\ts_barrier" ::: "memory");        \
        /* Z[c][nq] += Xg * P */                                               \
        _Pragma("unroll")                                                      \
        for (int kk2 = 0; kk2 < 2; ++kk2)                                      \
            _Pragma("unroll")                                                  \
            for (int nqs = 0; nqs < 2; ++nqs) {                                \
                short8 pbf = *(const short8*)(PB + (16 * nqs + l15) * 72       \
                                              + kk2 * 32 + q * 8);             \
                Zacc[0][nqs] = mfma16(xg[0][kk2], pbf, Zacc[0][nqs]);          \
                Zacc[1][nqs] = mfma16(xg[1][kk2], pbf, Zacc[1][nqs]);          \
                Zacc[2][nqs] = mfma16(xg[2][kk2], pbf, Zacc[2][nqs]);          \
                Zacc[3][nqs] = mfma16(xg[3][kk2], pbf, Zacc[3][nqs]);          \
            }                                                                  \
    }

__global__ __launch_bounds__(256, 2) void k_fused(
        const unsigned short* __restrict__ xB,    // S frags
        const unsigned short* __restrict__ xG,    // G2 A frags
        const unsigned short* __restrict__ wF,    // W A-frags
        const float* __restrict__ bias,
        const float* __restrict__ invn,           // [B][N]
        float* __restrict__ out) {                // [B][C][N] f32
    int blk = blockIdx.x;            // b*128 + qtile
    int b  = blk >> 7;
    int n0 = (blk & 127) << 5;
    int t  = threadIdx.x;
    int wv = t >> 6, lane = t & 63;
    int l15 = lane & 15, q = lane >> 4;
    int ms = wv;                     // S m-subtile = wave id

    __shared__ unsigned short pbuf[2][32 * 72];   // [parity][nq row][72 m]
    __shared__ unsigned short zbuf[32 * 264];     // dedicated
    __shared__ float spbuf2[4][32];               // colsum partials [ms][nq]

    const unsigned short* xBb = xB + (size_t)b * 256 * 8 * 512;
    const unsigned short* xGb = xG + (size_t)b * 64 * 16 * 1024;
    const float* invb = invn + b * NN;

    // persistent Xq A-frags from xB (coalesced); nq-subtiles {0,1}
    short8 aq[2][8];
    #pragma unroll
    for (int s = 0; s < 2; ++s)
        #pragma unroll
        for (int kk = 0; kk < 8; ++kk)
            aq[s][kk] = *(const short8*)(xBb
                + ((size_t)((n0 >> 4) + s) * 8 + kk) * 512 + lane * 8);
    float invq[2][4];
    #pragma unroll
    for (int s = 0; s < 2; ++s)
        #pragma unroll
        for (int i = 0; i < 4; ++i)
            invq[s][i] = invb[n0 + 16 * s + q * 4 + i];

    floatx4 zero4 = {0.f, 0.f, 0.f, 0.f};
    floatx4 Zacc[4][2];              // [ci: ct=wv+4ci][nqs]
    #pragma unroll
    for (int ci = 0; ci < 4; ++ci)
        #pragma unroll
        for (int nqs = 0; nqs < 2; ++nqs) Zacc[ci][nqs] = zero4;
    float csum[2][4];
    #pragma unroll
    for (int s = 0; s < 2; ++s)
        #pragma unroll
        for (int i = 0; i < 4; ++i) csum[s][i] = 0.f;

    // prologue: key tile 0 into bqA
    short8 bqA[8], bqB[8];
    #pragma unroll
    for (int kk = 0; kk < 8; ++kk)
        bqA[kk] = *(const short8*)(xBb + ((size_t)(ms) * 8 + kk) * 512 + lane * 8);

    for (int it2 = 0; it2 < 32; ++it2) {
        int itE = 2 * it2;
        FUSED_STEP(itE, bqA, bqB, (pbuf[0]));
        int itO = 2 * it2 + 1;
        FUSED_STEP(itO, bqB, bqA, (pbuf[1]));
    }

    // ---- colsum reduce over l15 (16-lane groups; pure f32) ----
    #pragma unroll
    for (int mask = 1; mask < 16; mask <<= 1)
        #pragma unroll
        for (int s = 0; s < 2; ++s)
            #pragma unroll
            for (int i = 0; i < 4; ++i)
                csum[s][i] += __shfl_xor(csum[s][i], mask, 64);

    __syncthreads();
    // Z -> zbuf (packed 8B stores; D: row=c-local=4q+i, col=nq=l15)
    #pragma unroll
    for (int ci = 0; ci < 4; ++ci) {
        int ct = wv + 4 * ci;
        #pragma unroll
        for (int nqs = 0; nqs < 2; ++nqs) {
            unsigned int lo = f2bf(Zacc[ci][nqs][0]) | ((unsigned int)f2bf(Zacc[ci][nqs][1]) << 16);
            unsigned int hi = f2bf(Zacc[ci][nqs][2]) | ((unsigned int)f2bf(Zacc[ci][nqs][3]) << 16);
            uint2v pz = {lo, hi};
            *(uint2v*)(&zbuf[(16 * nqs + l15) * 264 + 16 * ct + 4 * q]) = pz;
        }
    }
    if (l15 == 0) {
        #pragma unroll
        for (int s = 0; s < 2; ++s)
            #pragma unroll
            for (int i = 0; i < 4; ++i)
                spbuf2[ms][16 * s + 4 * q + i] = csum[s][i];
    }
    __syncthreads();

    float svals[2];
    #pragma unroll
    for (int nqs = 0; nqs < 2; ++nqs)
        svals[nqs] = spbuf2[0][16 * nqs + l15] + spbuf2[1][16 * nqs + l15]
                   + spbuf2[2][16 * nqs + l15] + spbuf2[3][16 * nqs + l15];

    // O = W*Z + b*svals
    float* ob = out + (size_t)b * CC * NN;
    floatx4 oa[4][2];
    #pragma unroll
    for (int ci = 0; ci < 4; ++ci) {
        int ct = wv + 4 * ci;
        floatx4 bv = *(const floatx4*)(bias + 16 * ct + 4 * q);
        #pragma unroll
        for (int nqs = 0; nqs < 2; ++nqs)
            #pragma unroll
            for (int i = 0; i < 4; ++i) oa[ci][nqs][i] = bv[i] * svals[nqs];
    }
    #pragma unroll
    for (int kk = 0; kk < 8; ++kk) {
        short8 zf0 = *(const short8*)(&zbuf[(l15) * 264 + 32 * kk + 8 * q]);
        short8 zf1 = *(const short8*)(&zbuf[(16 + l15) * 264 + 32 * kk + 8 * q]);
        #pragma unroll
        for (int ci = 0; ci < 4; ++ci) {
            int ct = wv + 4 * ci;
            short8 wf = *(const short8*)(wF + (size_t)(ct * 8 + kk) * 512 + lane * 8);
            oa[ci][0] = mfma16(wf, zf0, oa[ci][0]);
            oa[ci][1] = mfma16(wf, zf1, oa[ci][1]);
        }
    }
    #pragma unroll
    for (int ci = 0; ci < 4; ++ci) {
        int ct = wv + 4 * ci;
        #pragma unroll
        for (int nqs = 0; nqs < 2; ++nqs)
            #pragma unroll
            for (int i = 0; i < 4; ++i)
                ob[(size_t)(16 * ct + 4 * q + i) * NN + n0 + 16 * nqs + l15] = oa[ci][nqs][i];
    }
}

// ---------------------------------------------------------------------------
extern "C" void kernel_launch(void* const* d_in, const int* in_sizes, int n_in,
                              void* d_out, int out_size, void* d_ws, size_t ws_size,
                              hipStream_t stream) {
    const float* x    = (const float*)d_in[0];   // [4,256,64,64]
    const float* Wm   = (const float*)d_in[1];   // [256,256]
    const float* bias = (const float*)d_in[2];   // [256]
    float* out = (float*)d_out;

    // ws: psum 256KB | invn 64KB | xB 8MB | xG 8MB | wF 128KB  (~16.8MB)
    char* ws = (char*)d_ws;
    float* psum         = (float*)ws;
    float* invn         = (float*)(ws + 262144);
    unsigned short* xB  = (unsigned short*)(ws + 262144 + 65536);
    unsigned short* xG  = (unsigned short*)(ws + 262144 + 65536 + 8388608);
    unsigned short* wF  = (unsigned short*)(ws + 262144 + 65536 + 2 * 8388608);

    k_trans   <<<1024, 256, 0, stream>>>(x, xB, xG, psum);
    k_invwcast<<<96,   256, 0, stream>>>(psum, invn, Wm, wF);
    k_fused   <<<512,  256, 0, stream>>>(xB, xG, wF, bias, invn, out);
}

// Round 10
// 154.641 us; speedup vs baseline: 1.1056x; 1.1056x over previous
//
#include <hip/hip_runtime.h>
#include <stdint.h>

#define CC 256
#define NN 4096   // H*W = 64*64

typedef __attribute__((ext_vector_type(8))) short short8;
typedef __attribute__((ext_vector_type(4))) float floatx4;
typedef __attribute__((ext_vector_type(4))) unsigned int uint4v;
typedef __attribute__((ext_vector_type(2))) unsigned int uint2v;

__device__ __forceinline__ unsigned short f2bf(float f) {
    unsigned int u = __builtin_bit_cast(unsigned int, f);
    u = (u + 0x7FFFu + ((u >> 16) & 1u)) >> 16;   // RNE
    return (unsigned short)u;
}

__device__ __forceinline__ floatx4 mfma16(short8 a, short8 b, floatx4 c) {
    return __builtin_amdgcn_mfma_f32_16x16x32_bf16(a, b, c, 0, 0, 0);
}

// ---------------------------------------------------------------------------
// Fragment layouts (16x16x32 bf16; A-frag == B-frag lane map:
//   element(row = 16*tile + (lane&15), k = 32*kk + (lane>>4)*8 + j)):
// xB[b][nt 256][kk 8][lane][j] : row = n (pixel), k = c   (S operands)
// xG[b][mt 64][cct 16][kk2 2][lane][j] : row = c, k = m   (G2 A-operand)
// wF[ct 16][kk 8][lane][j]     : row = out-c, k = in-c    (epilogue A)
// ---------------------------------------------------------------------------

// ---------------------------------------------------------------------------
// k_trans (R8 verbatim): x -> xB + xG + partial norms psum.
// ---------------------------------------------------------------------------
__global__ __launch_bounds__(256) void k_trans(const float* __restrict__ x,
                                               unsigned short* __restrict__ xB,
                                               unsigned short* __restrict__ xG,
                                               float* __restrict__ psum) {
    int blk = blockIdx.x;
    int b  = blk >> 8;
    int cc = (blk >> 6) & 3;
    int nc = blk & 63;
    int c0 = cc << 6, n0 = nc << 6;
    __shared__ float tile[64][65];
    __shared__ float red[4][64];
    int t = threadIdx.x;
    {
        int c   = t >> 2;
        int nn4 = (t & 3) << 4;
        const float* src = x + (size_t)(b * CC + c0 + c) * NN + n0 + nn4;
        #pragma unroll
        for (int j = 0; j < 16; j += 4) {
            floatx4 v = *(const floatx4*)(src + j);
            tile[c][nn4 + j + 0] = v[0];
            tile[c][nn4 + j + 1] = v[1];
            tile[c][nn4 + j + 2] = v[2];
            tile[c][nn4 + j + 3] = v[3];
        }
    }
    __syncthreads();
    int g = t >> 6, lane = t & 63, l15 = lane & 15, q = lane >> 4;
    #pragma unroll
    for (int kkl = 0; kkl < 2; ++kkl) {
        unsigned int w[4];
        #pragma unroll
        for (int j = 0; j < 4; ++j) {
            unsigned int lo = f2bf(tile[32 * kkl + 8 * q + 2 * j][16 * g + l15]);
            unsigned int hi = f2bf(tile[32 * kkl + 8 * q + 2 * j + 1][16 * g + l15]);
            w[j] = lo | (hi << 16);
        }
        uint4v p = {w[0], w[1], w[2], w[3]};
        *(uint4v*)(xB + ((size_t)(b * 256 + (n0 >> 4) + g) * 8 + (c0 >> 5) + kkl) * 512
                   + lane * 8) = p;
    }
    #pragma unroll
    for (int kk2 = 0; kk2 < 2; ++kk2) {
        unsigned int w[4];
        #pragma unroll
        for (int j = 0; j < 4; ++j) {
            unsigned int lo = f2bf(tile[16 * g + l15][32 * kk2 + 8 * q + 2 * j]);
            unsigned int hi = f2bf(tile[16 * g + l15][32 * kk2 + 8 * q + 2 * j + 1]);
            w[j] = lo | (hi << 16);
        }
        uint4v p = {w[0], w[1], w[2], w[3]};
        *(uint4v*)(xG + (size_t)(b * 64 + nc) * 16 * 1024
                   + ((size_t)((c0 >> 4) + g)) * 1024 + kk2 * 512 + lane * 8) = p;
    }
    {
        int n  = t & 63;
        int cq = t >> 6;
        float ss = 0.f;
        #pragma unroll
        for (int i = 0; i < 16; ++i) {
            float v = tile[cq * 16 + i][n];
            ss = fmaf(v, v, ss);
        }
        red[cq][n] = ss;
    }
    __syncthreads();
    if (t < 64) {
        float s = red[0][t] + red[1][t] + red[2][t] + red[3][t];
        psum[((size_t)(b * 64 + nc) * 64 + t) * 4 + cc] = s;
    }
}

// ---------------------------------------------------------------------------
// k_invwcast (R8 verbatim)
// ---------------------------------------------------------------------------
__global__ __launch_bounds__(256) void k_invwcast(const float* __restrict__ psum,
                                                  float* __restrict__ invn,
                                                  const float* __restrict__ Wm,
                                                  unsigned short* __restrict__ wF) {
    int bid = blockIdx.x;
    int t = threadIdx.x;
    if (bid < 64) {
        int i = bid * 256 + t;
        floatx4 p = *(const floatx4*)(psum + (size_t)i * 4);
        float ss = (p[0] + p[1]) + (p[2] + p[3]);
        invn[i] = 1.f / fmaxf(sqrtf(ss), 1e-8f);
    } else {
        int idx = (bid - 64) * 256 + t;          // 0..8191
        int f = idx >> 6, lane = idx & 63;
        int ct = f >> 3, kk = f & 7;
        int l15 = lane & 15, q = lane >> 4;
        const float* src = Wm + (size_t)(16 * ct + l15) * CC + 32 * kk + 8 * q;
        floatx4 a = *(const floatx4*)src;
        floatx4 c = *(const floatx4*)(src + 4);
        unsigned int w0 = f2bf(a[0]) | ((unsigned int)f2bf(a[1]) << 16);
        unsigned int w1 = f2bf(a[2]) | ((unsigned int)f2bf(a[3]) << 16);
        unsigned int w2 = f2bf(c[0]) | ((unsigned int)f2bf(c[1]) << 16);
        unsigned int w3 = f2bf(c[2]) | ((unsigned int)f2bf(c[3]) << 16);
        uint4v p = {w0, w1, w2, w3};
        *(uint4v*)(wF + (size_t)f * 512 + lane * 8) = p;
    }
}

// ---------------------------------------------------------------------------
// k_fused v9: R8 frame (Q=64, 512 thr, grid 256) + pipelined G2 (deferred
// one step behind S, so the P ds_write -> ds_read distance is a full step),
// transposed S (D rows = m: packed b64 P-writes via __byte_perm round-half-
// up), pointer-increment addressing. One lgkm-only barrier/step.
// Wave wv: ms=wv&3, nq-subtiles {2np,2np+1} (np=wv>>2); G2 ct {wv, wv+8}.
// ---------------------------------------------------------------------------
#define FUSED_STEP(IT, BQC, BQN, XGP, XGC, DO_G2)                              \
    {                                                                          \
        /* issue next key tile + this step's xg (consumed next step) */        \
        _Pragma("unroll")                                                      \
        for (int kk = 0; kk < 8; ++kk)                                         \
            BQN[kk] = *(const short8*)(bqp + kk * 512);                        \
        bqp += 16384;                                                          \
        _Pragma("unroll")                                                      \
        for (int ci = 0; ci < 2; ++ci)                                         \
            _Pragma("unroll")                                                  \
            for (int kk2 = 0; kk2 < 2; ++kk2)                                  \
                XGC[ci][kk2] = *(const short8*)(xgp + ci * 8192 + kk2 * 512);  \
        xgp += 16384;                                                          \
        floatx4 invm4 = *(const floatx4*)invmp;                                \
        invmp += 64;                                                           \
        /* G2(IT-1): pbuf[(IT-1)&1] x prev xg */                               \
        if (DO_G2) {                                                           \
            const unsigned short* pbR = pbuf[((IT) - 1) & 1];                  \
            _Pragma("unroll")                                                  \
            for (int kk2 = 0; kk2 < 2; ++kk2)                                  \
                _Pragma("unroll")                                              \
                for (int nqs = 0; nqs < 4; ++nqs) {                            \
                    short8 pbf = *(const short8*)(pbR + (16 * nqs + l15) * 72  \
                                                  + kk2 * 32 + q * 8);         \
                    Zacc[0][nqs] = mfma16(XGP[0][kk2], pbf, Zacc[0][nqs]);     \
                    Zacc[1][nqs] = mfma16(XGP[1][kk2], pbf, Zacc[1][nqs]);     \
                }                                                              \
        }                                                                      \
        /* S(IT) transposed: A=keys, B=queries -> D rows = m-local */          \
        floatx4 s0a = zero4, s0b = zero4, s1a = zero4, s1b = zero4;            \
        _Pragma("unroll")                                                      \
        for (int kk = 0; kk < 8; kk += 2) {                                    \
            s0a = mfma16(BQC[kk],     aq[0][kk],     s0a);                     \
            s1a = mfma16(BQC[kk],     aq[1][kk],     s1a);                     \
            s0b = mfma16(BQC[kk + 1], aq[0][kk + 1], s0b);                     \
            s1b = mfma16(BQC[kk + 1], aq[1][kk + 1], s1b);                     \
        }                                                                      \
        /* P(IT) = relu(S*inv)^2 -> packed b64 -> pbuf[IT&1]; csum */          \
        {                                                                      \
            unsigned short* pbW = pbuf[(IT) & 1];                              \
            _Pragma("unroll")                                                  \
            for (int s = 0; s < 2; ++s) {                                      \
                floatx4 sv = (s == 0) ? (s0a + s0b) : (s1a + s1b);             \
                unsigned int pk0, pk1;                                         \
                float v0 = sv[0] * (invm4[0] * invq[s]);                       \
                float v1 = sv[1] * (invm4[1] * invq[s]);                       \
                float v2 = sv[2] * (invm4[2] * invq[s]);                       \
                float v3 = sv[3] * (invm4[3] * invq[s]);                       \
                v0 = fmaxf(v0, 0.f); v1 = fmaxf(v1, 0.f);                      \
                v2 = fmaxf(v2, 0.f); v3 = fmaxf(v3, 0.f);                      \
                v0 *= v0; v1 *= v1; v2 *= v2; v3 *= v3;                        \
                csum[s] += (v0 + v1) + (v2 + v3);                              \
                pk0 = __byte_perm(__builtin_bit_cast(unsigned int, v0) + 0x8000u, \
                                  __builtin_bit_cast(unsigned int, v1) + 0x8000u, \
                                  0x7632);                                     \
                pk1 = __byte_perm(__builtin_bit_cast(unsigned int, v2) + 0x8000u, \
                                  __builtin_bit_cast(unsigned int, v3) + 0x8000u, \
                                  0x7632);                                     \
                uint2v w2 = {pk0, pk1};                                        \
                *(uint2v*)(pbW + (16 * (2 * np + s) + l15) * 72                \
                           + 16 * ms + 4 * q) = w2;                            \
            }                                                                  \
        }                                                                      \
        asm volatile("s_waitcnt lgkmcnt(0)\n\ts_barrier" ::: "memory");        \
    }

__global__ __launch_bounds__(512, 1) void k_fused(
        const unsigned short* __restrict__ xB,    // S frags
        const unsigned short* __restrict__ xG,    // G2 A frags
        const unsigned short* __restrict__ wF,    // W A-frags
        const float* __restrict__ bias,
        const float* __restrict__ invn,           // [B][N]
        float* __restrict__ out) {                // [B][C][N] f32
    int blk = blockIdx.x;            // b*64 + qtile
    int b  = blk >> 6;
    int n0 = (blk & 63) << 6;
    int t  = threadIdx.x;
    int wv = t >> 6, lane = t & 63;
    int l15 = lane & 15, q = lane >> 4;
    int ms = wv & 3;
    int np = wv >> 2;                // nq pair {2np, 2np+1}

    __shared__ unsigned short pbuf[2][64 * 72];   // [parity][nq row][72 m]
    __shared__ unsigned short zbuf[64 * 264];     // dedicated
    __shared__ float spbuf2[4][64];               // colsum partials [ms][nq]

    const unsigned short* xBb = xB + (size_t)b * 256 * 8 * 512;
    const unsigned short* xGb = xG + (size_t)b * 64 * 16 * 1024;
    const float* invb = invn + b * NN;

    // persistent Xq frags (B operand of transposed S)
    short8 aq[2][8];
    #pragma unroll
    for (int s = 0; s < 2; ++s)
        #pragma unroll
        for (int kk = 0; kk < 8; ++kk)
            aq[s][kk] = *(const short8*)(xBb
                + ((size_t)((n0 >> 4) + 2 * np + s) * 8 + kk) * 512 + lane * 8);
    float invq[2];
    #pragma unroll
    for (int s = 0; s < 2; ++s) invq[s] = invb[n0 + 16 * (2 * np + s) + l15];

    floatx4 zero4 = {0.f, 0.f, 0.f, 0.f};
    floatx4 Zacc[2][4];              // [ci: cct=wv+8ci][nqs]
    #pragma unroll
    for (int ci = 0; ci < 2; ++ci)
        #pragma unroll
        for (int nqs = 0; nqs < 4; ++nqs) Zacc[ci][nqs] = zero4;
    float csum[2] = {0.f, 0.f};

    // hot-loop pointers (constant strides)
    const unsigned short* bqp   = xBb + ms * 4096 + lane * 8;      // tile 0
    const unsigned short* xgp   = xGb + wv * 1024 + lane * 8;      // xg(0)
    const float*          invmp = invb + 16 * ms + 4 * q;          // m-tile 0

    short8 bqA[8], bqB[8];
    short8 xgA[2][2], xgB[2][2];
    #pragma unroll
    for (int kk = 0; kk < 8; ++kk)
        bqA[kk] = *(const short8*)(bqp + kk * 512);
    bqp += 16384;

    // peel it=0 (no G2 yet); loads xg(0) into xgA
    FUSED_STEP(0, bqA, bqB, xgB, xgA, false)
    // pairs it = 1..62
    for (int it2 = 0; it2 < 31; ++it2) {
        int itO = 2 * it2 + 1;
        FUSED_STEP(itO, bqB, bqA, xgA, xgB, true)
        int itE = 2 * it2 + 2;
        FUSED_STEP(itE, bqA, bqB, xgB, xgA, true)
    }
    // it = 63
    FUSED_STEP(63, bqB, bqA, xgA, xgB, true)
    // final G2(63): pbuf[1] x xgB
    {
        const unsigned short* pbR = pbuf[1];
        #pragma unroll
        for (int kk2 = 0; kk2 < 2; ++kk2)
            #pragma unroll
            for (int nqs = 0; nqs < 4; ++nqs) {
                short8 pbf = *(const short8*)(pbR + (16 * nqs + l15) * 72
                                              + kk2 * 32 + q * 8);
                Zacc[0][nqs] = mfma16(xgB[0][kk2], pbf, Zacc[0][nqs]);
                Zacc[1][nqs] = mfma16(xgB[1][kk2], pbf, Zacc[1][nqs]);
            }
    }

    // ---- colsum reduce over q-groups (lanes ^16, ^32) ----
    #pragma unroll
    for (int s = 0; s < 2; ++s) {
        csum[s] += __shfl_xor(csum[s], 16, 64);
        csum[s] += __shfl_xor(csum[s], 32, 64);
    }

    __syncthreads();
    // Z -> zbuf (scalar stores, dedicated LDS)
    #pragma unroll
    for (int ci = 0; ci < 2; ++ci) {
        int cct = wv + 8 * ci;
        #pragma unroll
        for (int nqs = 0; nqs < 4; ++nqs)
            #pragma unroll
            for (int i = 0; i < 4; ++i)
                zbuf[(16 * nqs + l15) * 264 + 16 * cct + 4 * q + i] = f2bf(Zacc[ci][nqs][i]);
    }
    if (q == 0) {
        #pragma unroll
        for (int s = 0; s < 2; ++s)
            spbuf2[ms][16 * (2 * np + s) + l15] = csum[s];
    }
    __syncthreads();

    float svals[4];
    #pragma unroll
    for (int nqs = 0; nqs < 4; ++nqs)
        svals[nqs] = spbuf2[0][16 * nqs + l15] + spbuf2[1][16 * nqs + l15]
                   + spbuf2[2][16 * nqs + l15] + spbuf2[3][16 * nqs + l15];

    // O = W*Z + b*svals
    float* ob = out + (size_t)b * CC * NN;
    floatx4 oa[2][4];
    #pragma unroll
    for (int ci = 0; ci < 2; ++ci) {
        int ct = wv + 8 * ci;
        floatx4 bv = *(const floatx4*)(bias + 16 * ct + 4 * q);
        #pragma unroll
        for (int nqs = 0; nqs < 4; ++nqs)
            #pragma unroll
            for (int i = 0; i < 4; ++i) oa[ci][nqs][i] = bv[i] * svals[nqs];
    }
    #pragma unroll
    for (int kk = 0; kk < 8; ++kk) {
        short8 wf0 = *(const short8*)(wF + (size_t)(wv * 8 + kk) * 512 + lane * 8);
        short8 wf1 = *(const short8*)(wF + (size_t)((wv + 8) * 8 + kk) * 512 + lane * 8);
        #pragma unroll
        for (int nqs = 0; nqs < 4; ++nqs) {
            short8 zf = *(const short8*)(&zbuf[(16 * nqs + l15) * 264 + 32 * kk + 8 * q]);
            oa[0][nqs] = mfma16(wf0, zf, oa[0][nqs]);
            oa[1][nqs] = mfma16(wf1, zf, oa[1][nqs]);
        }
    }
    #pragma unroll
    for (int ci = 0; ci < 2; ++ci) {
        int ct = wv + 8 * ci;
        #pragma unroll
        for (int nqs = 0; nqs < 4; ++nqs)
            #pragma unroll
            for (int i = 0; i < 4; ++i)
                ob[(size_t)(16 * ct + 4 * q + i) * NN + n0 + 16 * nqs + l15] = oa[ci][nqs][i];
    }
}

// ---------------------------------------------------------------------------
extern "C" void kernel_launch(void* const* d_in, const int* in_sizes, int n_in,
                              void* d_out, int out_size, void* d_ws, size_t ws_size,
                              hipStream_t stream) {
    const float* x    = (const float*)d_in[0];   // [4,256,64,64]
    const float* Wm   = (const float*)d_in[1];   // [256,256]
    const float* bias = (const float*)d_in[2];   // [256]
    float* out = (float*)d_out;

    // ws: psum 256KB | invn 64KB | xB 8MB | xG 8MB | wF 128KB  (~16.8MB)
    char* ws = (char*)d_ws;
    float* psum         = (float*)ws;
    float* invn         = (float*)(ws + 262144);
    unsigned short* xB  = (unsigned short*)(ws + 262144 + 65536);
    unsigned short* xG  = (unsigned short*)(ws + 262144 + 65536 + 8388608);
    unsigned short* wF  = (unsigned short*)(ws + 262144 + 65536 + 2 * 8388608);

    k_trans   <<<1024, 256, 0, stream>>>(x, xB, xG, psum);
    k_invwcast<<<96,   256, 0, stream>>>(psum, invn, Wm, wF);
    k_fused   <<<256,  512, 0, stream>>>(xB, xG, wF, bias, invn, out);
}